// Round 6
// baseline (568.843 us; speedup 1.0000x reference)
//
#include <hip/hip_runtime.h>
#include <math.h>

#define B_ 128
#define N_ 128
#define D_ 64
#define H_ 8
#define DH_ 64
#define NEGF (-1e30f)

__device__ __forceinline__ float wred(float v) {
#pragma unroll
  for (int off = 32; off > 0; off >>= 1) v += __shfl_xor(v, off, 64);
  return v;
}

__device__ __forceinline__ float gelu_f(float x) {
  return 0.5f * x * (1.f + erff(x * 0.70710678118654752440f));
}

// K2: fused embed + RMS + LN1 + projections. grid (512, 3): blockIdx.x = 32-row
// tile, blockIdx.y = chunk (Wq|Wk|Wv + 8 gate cols). Register tile: each thread
// 16 rows x 4 cols; LDS hs reads are full-wave broadcasts (1 b128 -> 16 FMA).
__global__ void __launch_bounds__(256) k2_embed_proj(
    const float* __restrict__ x, const float* __restrict__ Wemb,
    const float* __restrict__ bemb, const float* __restrict__ rmsg,
    const float* __restrict__ ln1g, const float* __restrict__ ln1b,
    const float* __restrict__ Wq, const float* __restrict__ Wk,
    const float* __restrict__ Wv, const float* __restrict__ Wg,
    const float* __restrict__ bg, float* __restrict__ e,
    float* __restrict__ lne, float* __restrict__ q,
    float* __restrict__ k, float* __restrict__ v, float* __restrict__ g) {
  __shared__ __align__(16) float hs[32 * 68];  // row stride 68: rows spread banks
  int tid = threadIdx.x;
  int r0 = blockIdx.x * 32;
  int chunk = blockIdx.y;
  int wave = tid >> 6, lane = tid & 63;
  // ---- embed + RMS + LN1 (8 rows per wave; chunk 0 writes e/lne) ----
  for (int rr = 0; rr < 8; ++rr) {
    int r = wave * 8 + rr;
    int row = r0 + r;
    float xv = x[row];
    float ev = fmaf(xv, Wemb[lane], bemb[lane]);
    float ss = wred(ev * ev) * (1.f / 64.f);
    float hv = ev * rsqrtf(ss + 1e-6f) * rmsg[lane];
    float mu = wred(ev) * (1.f / 64.f);
    float dv = ev - mu;
    float var = wred(dv * dv) * (1.f / 64.f);
    if (chunk == 0) {
      float lv = dv * rsqrtf(var + 1e-5f) * ln1g[lane] + ln1b[lane];
      size_t o = (size_t)row * 64 + lane;
      e[o] = ev; lne[o] = lv;
    }
    hs[r * 68 + lane] = hv;
  }
  __syncthreads();
  const float* W = (chunk == 0) ? Wq : ((chunk == 1) ? Wk : Wv);
  float* dst = (chunk == 0) ? q : ((chunk == 1) ? k : v);
  // ---- main GEMM: 32 rows x 512 cols; thread = 16 rows x 4 cols ----
  {
    int tx = tid & 127, ty = tid >> 7;  // cols 4*tx, rows ty*16..ty*16+15
    float4 acc[16];
#pragma unroll
    for (int r = 0; r < 16; ++r) acc[r] = make_float4(0.f, 0.f, 0.f, 0.f);
    const float* Wp = W + 4 * tx;
#pragma unroll 2
    for (int k4 = 0; k4 < 16; ++k4) {
      float4 w0 = *(const float4*)(Wp + (size_t)(4 * k4 + 0) * 512);
      float4 w1 = *(const float4*)(Wp + (size_t)(4 * k4 + 1) * 512);
      float4 w2 = *(const float4*)(Wp + (size_t)(4 * k4 + 2) * 512);
      float4 w3 = *(const float4*)(Wp + (size_t)(4 * k4 + 3) * 512);
#pragma unroll
      for (int r = 0; r < 16; ++r) {
        float4 hv = *(const float4*)&hs[(ty * 16 + r) * 68 + 4 * k4];
        acc[r].x = fmaf(hv.x, w0.x, fmaf(hv.y, w1.x, fmaf(hv.z, w2.x, fmaf(hv.w, w3.x, acc[r].x))));
        acc[r].y = fmaf(hv.x, w0.y, fmaf(hv.y, w1.y, fmaf(hv.z, w2.y, fmaf(hv.w, w3.y, acc[r].y))));
        acc[r].z = fmaf(hv.x, w0.z, fmaf(hv.y, w1.z, fmaf(hv.z, w2.z, fmaf(hv.w, w3.z, acc[r].z))));
        acc[r].w = fmaf(hv.x, w0.w, fmaf(hv.y, w1.w, fmaf(hv.z, w2.w, fmaf(hv.w, w3.w, acc[r].w))));
      }
    }
    int hh = (4 * tx) >> 6, d4 = (4 * tx) & 63;
    int bb = r0 >> 7;
    float* dbase = dst + ((size_t)(bb * 8 + hh) * 128) * 64 + d4;
#pragma unroll
    for (int r = 0; r < 16; ++r) {
      int nn = (r0 & 127) + ty * 16 + r;
      *(float4*)(dbase + (size_t)nn * 64) = acc[r];
    }
  }
  // ---- gate: 8 cols (chunk*8 .. +8) x 32 rows; thread = 1 output ----
  {
    int r = tid >> 3, gl = tid & 7;
    int gc = chunk * 8 + gl;
    float a = bg[gc];
#pragma unroll 4
    for (int k4 = 0; k4 < 16; ++k4) {
      float4 hv = *(const float4*)&hs[r * 68 + 4 * k4];
      a = fmaf(hv.x, Wg[(4 * k4 + 0) * 24 + gc],
          fmaf(hv.y, Wg[(4 * k4 + 1) * 24 + gc],
          fmaf(hv.z, Wg[(4 * k4 + 2) * 24 + gc],
          fmaf(hv.w, Wg[(4 * k4 + 3) * 24 + gc], a))));
    }
    g[(size_t)(r0 + r) * 24 + gc] = 1.f / (1.f + __expf(-a));
  }
}

// K3: per (b,h): ck = (k+kpos)@Wck+bck ; cv = (v+vpos)@Wcv+bcv; mem slot 0.
// Thread = 2 rows x 4 cols. LDS block-row stride 260 floats (256 + 4 pad).
__global__ void __launch_bounds__(256) k3_compress(
    const float* __restrict__ k, const float* __restrict__ v,
    const float* __restrict__ kpos, const float* __restrict__ vpos,
    const float* __restrict__ Wck, const float* __restrict__ bck,
    const float* __restrict__ Wcv, const float* __restrict__ bcv,
    const float* __restrict__ mck, const float* __restrict__ mcv,
    float* __restrict__ ckm, float* __restrict__ cvm) {
  __shared__ __align__(16) float sb[32 * 260];
  int bh = blockIdx.x; int hh = bh & 7;
  int tid = threadIdx.x;
  int tx = tid & 15, ty = tid >> 4;  // cols 4*tx; rows {ty, ty+16}
  const float4* sb4 = (const float4*)sb;  // block-row stride 65 float4
  for (int pass = 0; pass < 2; ++pass) {
    const float* src = pass ? v : k;
    const float* pos = pass ? vpos : kpos;
    const float* Wc = pass ? Wcv : Wck;
    const float* bc = pass ? bcv : bck;
    const float* mc = pass ? mcv : mck;
    float* out = pass ? cvm : ckm;
    if (pass) __syncthreads();
    for (int idx = tid; idx < 8192; idx += 256) {
      int tok = idx >> 6, dd = idx & 63;
      // block-row = tok>>2, within-row offset = (tok&3)*64 + dd  (stride 260)
      sb[(tok >> 2) * 260 + (tok & 3) * 64 + dd] =
          src[(size_t)bh * 8192 + idx] + pos[(hh * 4 + (tok & 3)) * 64 + dd];
    }
    __syncthreads();
    float4 b4 = *(const float4*)(bc + 4 * tx);
    float4 a0 = b4, a1 = b4;
    const float* Wp = Wc + 4 * tx;
#pragma unroll 2
    for (int k4 = 0; k4 < 64; ++k4) {
      float4 w0 = *(const float4*)(Wp + (size_t)(4 * k4 + 0) * 64);
      float4 w1 = *(const float4*)(Wp + (size_t)(4 * k4 + 1) * 64);
      float4 w2 = *(const float4*)(Wp + (size_t)(4 * k4 + 2) * 64);
      float4 w3 = *(const float4*)(Wp + (size_t)(4 * k4 + 3) * 64);
      float4 s0 = sb4[ty * 65 + k4];
      float4 s1 = sb4[(ty + 16) * 65 + k4];
      a0.x = fmaf(s0.x, w0.x, fmaf(s0.y, w1.x, fmaf(s0.z, w2.x, fmaf(s0.w, w3.x, a0.x))));
      a0.y = fmaf(s0.x, w0.y, fmaf(s0.y, w1.y, fmaf(s0.z, w2.y, fmaf(s0.w, w3.y, a0.y))));
      a0.z = fmaf(s0.x, w0.z, fmaf(s0.y, w1.z, fmaf(s0.z, w2.z, fmaf(s0.w, w3.z, a0.z))));
      a0.w = fmaf(s0.x, w0.w, fmaf(s0.y, w1.w, fmaf(s0.z, w2.w, fmaf(s0.w, w3.w, a0.w))));
      a1.x = fmaf(s1.x, w0.x, fmaf(s1.y, w1.x, fmaf(s1.z, w2.x, fmaf(s1.w, w3.x, a1.x))));
      a1.y = fmaf(s1.x, w0.y, fmaf(s1.y, w1.y, fmaf(s1.z, w2.y, fmaf(s1.w, w3.y, a1.y))));
      a1.z = fmaf(s1.x, w0.z, fmaf(s1.y, w1.z, fmaf(s1.z, w2.z, fmaf(s1.w, w3.z, a1.z))));
      a1.w = fmaf(s1.x, w0.w, fmaf(s1.y, w1.w, fmaf(s1.z, w2.w, fmaf(s1.w, w3.w, a1.w))));
    }
    *(float4*)(out + ((size_t)bh * 33 + ty + 1) * 64 + 4 * tx) = a0;
    *(float4*)(out + ((size_t)bh * 33 + ty + 17) * 64 + 4 * tx) = a1;
    if (tid < 16) *(float4*)(out + (size_t)bh * 2112 + 4 * tid) = *(const float4*)(mc + hh * 64 + 4 * tid);
  }
}

// K4: per (b,h): compressed + selected + window attention, gated combine.
// 1 thread = 1 query; scores in registers; PV in two d-halves (VGPR relief).
#define KLD 68
__global__ void __launch_bounds__(128, 2) k4_attn(
    const float* __restrict__ q, const float* __restrict__ k, const float* __restrict__ v,
    const float* __restrict__ ckm, const float* __restrict__ cvm, const float* __restrict__ g,
    float* __restrict__ attn) {
  __shared__ __align__(16) float ks[128 * KLD];  // K rows, later reloaded with V
  int bh = blockIdx.x; int b = bh >> 3, hh = bh & 7;
  int tid = threadIdx.x;
  for (int idx = tid; idx < 8192; idx += 128)
    ks[(idx >> 6) * KLD + (idx & 63)] = k[(size_t)bh * 8192 + idx];
  __syncthreads();
  const int n = tid;
  float4 qr[16];
  {
    const float4* q4 = (const float4*)(q + (size_t)bh * 8192 + (size_t)n * 64);
#pragma unroll
    for (int i = 0; i < 16; ++i) {
      float4 t = q4[i];
      t.x *= 0.125f; t.y *= 0.125f; t.z *= 0.125f; t.w *= 0.125f;
      qr[i] = t;
    }
  }
  auto dot = [&](const float4* __restrict__ rp) {
    float s0 = 0.f, s1 = 0.f;
#pragma unroll
    for (int i = 0; i < 16; i += 2) {
      float4 c0 = rp[i], c1 = rp[i + 1];
      s0 = fmaf(qr[i].x, c0.x, s0); s0 = fmaf(qr[i].y, c0.y, s0);
      s0 = fmaf(qr[i].z, c0.z, s0); s0 = fmaf(qr[i].w, c0.w, s0);
      s1 = fmaf(qr[i + 1].x, c1.x, s1); s1 = fmaf(qr[i + 1].y, c1.y, s1);
      s1 = fmaf(qr[i + 1].z, c1.z, s1); s1 = fmaf(qr[i + 1].w, c1.w, s1);
    }
    return s0 + s1;
  };
  const float* ck0 = ckm + (size_t)bh * 2112;
  const int jmax = (n + 1) >> 2;
  float scc[33];
#pragma unroll
  for (int j = 0; j < 33; ++j) {
    float s = dot((const float4*)(ck0 + j * 64));
    scc[j] = (j == 0 || j <= jmax) ? s : NEGF;
  }
  // exact top-2 (strict >, first index wins = lax.top_k ties)
  int i1 = 0; float b1 = scc[1];
#pragma unroll
  for (int j = 2; j < 33; ++j) {
    if (scc[j] > b1) { b1 = scc[j]; i1 = j - 1; }
  }
  int i2 = 0; float b2 = -3.0e38f;
#pragma unroll
  for (int j = 1; j < 33; ++j) {
    if ((j - 1 != i1) && (scc[j] > b2)) { b2 = scc[j]; i2 = j - 1; }
  }
  const int qb = n >> 2;
  const bool ok1 = (b1 > -5e29f) && (i1 != qb);
  const bool ok2 = (b2 > -5e29f) && (i2 != qb);
  const int row1 = i1 * 4, row2 = i2 * 4, rowd = qb * 4;
  float sf[12];
#pragma unroll
  for (int s2 = 0; s2 < 4; ++s2) {
    int t1 = row1 + s2;
    sf[s2] = (ok1 && t1 <= n) ? dot((const float4*)(ks + t1 * KLD)) : NEGF;
    int t2 = row2 + s2;
    sf[4 + s2] = (ok2 && t2 <= n) ? dot((const float4*)(ks + t2 * KLD)) : NEGF;
    int t3 = rowd + s2;
    sf[8 + s2] = (t3 <= n) ? dot((const float4*)(ks + t3 * KLD)) : NEGF;
  }
  float sw0 = (n >= 1) ? dot((const float4*)(ks + (n - 1) * KLD)) : NEGF;
  float sw1 = dot((const float4*)(ks + n * KLD));
  __syncthreads();
  for (int idx = tid; idx < 8192; idx += 128)  // reload LDS with V
    ks[(idx >> 6) * KLD + (idx & 63)] = v[(size_t)bh * 8192 + idx];
  __syncthreads();
  // softmaxes
  float mxc = scc[0];
#pragma unroll
  for (int j = 1; j < 33; ++j) mxc = fmaxf(mxc, scc[j]);
  float denc = 0.f;
#pragma unroll
  for (int j = 0; j < 33; ++j) { float p = __expf(scc[j] - mxc); scc[j] = p; denc += p; }
  float mxf = sf[0];
#pragma unroll
  for (int i = 1; i < 12; ++i) mxf = fmaxf(mxf, sf[i]);
  float denf = 0.f;
#pragma unroll
  for (int i = 0; i < 12; ++i) { float p = __expf(sf[i] - mxf); sf[i] = p; denf += p; }
  float mxw = fmaxf(sw0, sw1);
  float pw0 = __expf(sw0 - mxw), pw1 = __expf(sw1 - mxw);
  const float* gr = g + (size_t)(b * 128 + n) * 24;
  float gc0 = gr[hh] / denc;
  float gf0 = gr[8 + hh] / denf;
  float gw0 = gr[16 + hh] / (pw0 + pw1);
  float pww0 = pw0 * gw0, pww1 = pw1 * gw0;
  int nm1 = (n >= 1) ? (n - 1) : 0;
  const float* cv0 = cvm + (size_t)bh * 2112;
  float4* arow = (float4*)(attn + ((size_t)(b * 128 + n)) * 512 + hh * 64);
  for (int h2 = 0; h2 < 2; ++h2) {  // PV in two d-halves (not unrolled)
    float4 oa[8];
#pragma unroll
    for (int i = 0; i < 8; ++i) oa[i] = make_float4(0.f, 0.f, 0.f, 0.f);
#pragma unroll
    for (int j = 0; j < 33; ++j) {
      float p = scc[j] * gc0;
      const float4* cr = (const float4*)(cv0 + j * 64) + h2 * 8;
#pragma unroll
      for (int i = 0; i < 8; ++i) {
        float4 c = cr[i];
        oa[i].x = fmaf(p, c.x, oa[i].x); oa[i].y = fmaf(p, c.y, oa[i].y);
        oa[i].z = fmaf(p, c.z, oa[i].z); oa[i].w = fmaf(p, c.w, oa[i].w);
      }
    }
#pragma unroll
    for (int si = 0; si < 12; ++si) {
      int tok = ((si < 4) ? row1 : (si < 8) ? row2 : rowd) + (si & 3);
      float p = sf[si] * gf0;
      const float4* vr = (const float4*)(ks + tok * KLD) + h2 * 8;
#pragma unroll
      for (int i = 0; i < 8; ++i) {
        float4 c = vr[i];
        oa[i].x = fmaf(p, c.x, oa[i].x); oa[i].y = fmaf(p, c.y, oa[i].y);
        oa[i].z = fmaf(p, c.z, oa[i].z); oa[i].w = fmaf(p, c.w, oa[i].w);
      }
    }
    {
      const float4* v0 = (const float4*)(ks + nm1 * KLD) + h2 * 8;
      const float4* v1 = (const float4*)(ks + n * KLD) + h2 * 8;
#pragma unroll
      for (int i = 0; i < 8; ++i) {
        float4 c0 = v0[i], c1 = v1[i];
        oa[i].x = fmaf(pww0, c0.x, fmaf(pww1, c1.x, oa[i].x));
        oa[i].y = fmaf(pww0, c0.y, fmaf(pww1, c1.y, oa[i].y));
        oa[i].z = fmaf(pww0, c0.z, fmaf(pww1, c1.z, oa[i].z));
        oa[i].w = fmaf(pww0, c0.w, fmaf(pww1, c1.w, oa[i].w));
      }
    }
#pragma unroll
    for (int i = 0; i < 8; ++i) arow[h2 * 8 + i] = oa[i];
  }
}

// K5: x1 = attn @ Wo. 16 rows/block; thread = 1 row x 4 cols.
__global__ void __launch_bounds__(256) k5_wo(const float* __restrict__ attn,
                                             const float* __restrict__ Wo,
                                             float* __restrict__ x1) {
  __shared__ __align__(16) float as[16 * 516];
  int tid = threadIdx.x;
  size_t base = (size_t)blockIdx.x * 8192;
  for (int idx = tid; idx < 8192; idx += 256)
    as[(idx >> 9) * 516 + (idx & 511)] = attn[base + idx];
  __syncthreads();
  int tx = tid & 15, ty = tid >> 4;  // cols 4*tx, row ty
  const float4* as4 = (const float4*)as;  // row stride 129 float4
  float4 acc = make_float4(0.f, 0.f, 0.f, 0.f);
  const float* Wp = Wo + 4 * tx;
#pragma unroll 4
  for (int k4 = 0; k4 < 128; ++k4) {
    float4 w0 = *(const float4*)(Wp + (size_t)(4 * k4 + 0) * 64);
    float4 w1 = *(const float4*)(Wp + (size_t)(4 * k4 + 1) * 64);
    float4 w2 = *(const float4*)(Wp + (size_t)(4 * k4 + 2) * 64);
    float4 w3 = *(const float4*)(Wp + (size_t)(4 * k4 + 3) * 64);
    float4 a = as4[ty * 129 + k4];
    acc.x = fmaf(a.x, w0.x, fmaf(a.y, w1.x, fmaf(a.z, w2.x, fmaf(a.w, w3.x, acc.x))));
    acc.y = fmaf(a.x, w0.y, fmaf(a.y, w1.y, fmaf(a.z, w2.y, fmaf(a.w, w3.y, acc.y))));
    acc.z = fmaf(a.x, w0.z, fmaf(a.y, w1.z, fmaf(a.z, w2.z, fmaf(a.w, w3.z, acc.z))));
    acc.w = fmaf(a.x, w0.w, fmaf(a.y, w1.w, fmaf(a.z, w2.w, fmaf(a.w, w3.w, acc.w))));
  }
  *(float4*)(x1 + ((size_t)blockIdx.x * 16 + ty) * 64 + 4 * tx) = acc;
}

// K6: token mixer. block = (b, 4 d-cols): m = e + (gelu(LN1^T@Wt1+bt1)@Wt2+bt2)^T
__global__ void __launch_bounds__(256) k6_token(
    const float* __restrict__ lne, const float* __restrict__ e,
    const float* __restrict__ Wt1, const float* __restrict__ bt1,
    const float* __restrict__ Wt2, const float* __restrict__ bt2,
    float* __restrict__ m) {
  __shared__ __align__(16) float trow[4 * 132];
  __shared__ __align__(16) float hid[4 * 260];
  int b = blockIdx.x >> 4, d0 = (blockIdx.x & 15) * 4;
  int tid = threadIdx.x;
  for (int idx = tid; idx < 512; idx += 256) {
    int nn = idx >> 2, dl = idx & 3;
    trow[dl * 132 + nn] = lne[((size_t)b * 128 + nn) * 64 + d0 + dl];
  }
  __syncthreads();
  {  // GEMM1: [4,128] @ Wt1[128,256]; thread = 1 row x 4 cols
    int tx = tid & 63, ty = tid >> 6;
    float4 acc = *(const float4*)(bt1 + 4 * tx);
    const float4* tr4 = (const float4*)&trow[ty * 132];
    const float* Wp = Wt1 + 4 * tx;
#pragma unroll 2
    for (int k4 = 0; k4 < 32; ++k4) {
      float4 w0 = *(const float4*)(Wp + (size_t)(4 * k4 + 0) * 256);
      float4 w1 = *(const float4*)(Wp + (size_t)(4 * k4 + 1) * 256);
      float4 w2 = *(const float4*)(Wp + (size_t)(4 * k4 + 2) * 256);
      float4 w3 = *(const float4*)(Wp + (size_t)(4 * k4 + 3) * 256);
      float4 t = tr4[k4];
      acc.x = fmaf(t.x, w0.x, fmaf(t.y, w1.x, fmaf(t.z, w2.x, fmaf(t.w, w3.x, acc.x))));
      acc.y = fmaf(t.x, w0.y, fmaf(t.y, w1.y, fmaf(t.z, w2.y, fmaf(t.w, w3.y, acc.y))));
      acc.z = fmaf(t.x, w0.z, fmaf(t.y, w1.z, fmaf(t.z, w2.z, fmaf(t.w, w3.z, acc.z))));
      acc.w = fmaf(t.x, w0.w, fmaf(t.y, w1.w, fmaf(t.z, w2.w, fmaf(t.w, w3.w, acc.w))));
    }
    float* hp = &hid[ty * 260 + 4 * tx];
    hp[0] = gelu_f(acc.x); hp[1] = gelu_f(acc.y); hp[2] = gelu_f(acc.z); hp[3] = gelu_f(acc.w);
  }
  __syncthreads();
  {  // GEMM2: [4,256] @ Wt2[256,128]; thread = 1 row x 2 cols
    int tx = tid & 63, ty = tid >> 6;
    float o0 = bt2[2 * tx], o1 = bt2[2 * tx + 1];
    const float4* h4 = (const float4*)&hid[ty * 260];
    const float* Wp = Wt2 + 2 * tx;
#pragma unroll 2
    for (int k4 = 0; k4 < 64; ++k4) {
      float2 w0 = *(const float2*)(Wp + (size_t)(4 * k4 + 0) * 128);
      float2 w1 = *(const float2*)(Wp + (size_t)(4 * k4 + 1) * 128);
      float2 w2 = *(const float2*)(Wp + (size_t)(4 * k4 + 2) * 128);
      float2 w3 = *(const float2*)(Wp + (size_t)(4 * k4 + 3) * 128);
      float4 t = h4[k4];
      o0 = fmaf(t.x, w0.x, fmaf(t.y, w1.x, fmaf(t.z, w2.x, fmaf(t.w, w3.x, o0))));
      o1 = fmaf(t.x, w0.y, fmaf(t.y, w1.y, fmaf(t.z, w2.y, fmaf(t.w, w3.y, o1))));
    }
    size_t oi0 = ((size_t)b * 128 + 2 * tx) * 64 + d0 + ty;
    size_t oi1 = oi0 + 64;
    m[oi0] = e[oi0] + o0;
    m[oi1] = e[oi1] + o1;
  }
}

// K7: channel MLP in-place: m += gelu(LN2(m)@Wc1+bc1)@Wc2+bc2. 8 rows/block.
__global__ void __launch_bounds__(256) k7_channel(
    float* __restrict__ m, const float* __restrict__ g2, const float* __restrict__ b2,
    const float* __restrict__ Wc1, const float* __restrict__ bc1,
    const float* __restrict__ Wc2, const float* __restrict__ bc2) {
  __shared__ __align__(16) float lnr[8 * 68];
  __shared__ __align__(16) float hid[8 * 260];
  int tid = threadIdx.x;
  int wv = tid >> 6, lane = tid & 63;
  size_t r0 = (size_t)blockIdx.x * 8;
  for (int rr = 0; rr < 2; ++rr) {
    int r = wv * 2 + rr;
    float mv = m[(r0 + r) * 64 + lane];
    float mu = wred(mv) * (1.f / 64.f);
    float dv = mv - mu;
    float var = wred(dv * dv) * (1.f / 64.f);
    lnr[r * 68 + lane] = dv * rsqrtf(var + 1e-5f) * g2[lane] + b2[lane];
  }
  __syncthreads();
  {  // GEMM1: [8,64] @ Wc1[64,256]; thread = 2 rows x 4 cols
    int tx = tid & 63, ty = tid >> 6;  // rows {ty, ty+4}
    float4 b4 = *(const float4*)(bc1 + 4 * tx);
    float4 a0 = b4, a1 = b4;
    const float4* l0 = (const float4*)&lnr[ty * 68];
    const float4* l1 = (const float4*)&lnr[(ty + 4) * 68];
    const float* Wp = Wc1 + 4 * tx;
#pragma unroll 2
    for (int k4 = 0; k4 < 16; ++k4) {
      float4 w0 = *(const float4*)(Wp + (size_t)(4 * k4 + 0) * 256);
      float4 w1 = *(const float4*)(Wp + (size_t)(4 * k4 + 1) * 256);
      float4 w2 = *(const float4*)(Wp + (size_t)(4 * k4 + 2) * 256);
      float4 w3 = *(const float4*)(Wp + (size_t)(4 * k4 + 3) * 256);
      float4 s0 = l0[k4], s1 = l1[k4];
      a0.x = fmaf(s0.x, w0.x, fmaf(s0.y, w1.x, fmaf(s0.z, w2.x, fmaf(s0.w, w3.x, a0.x))));
      a0.y = fmaf(s0.x, w0.y, fmaf(s0.y, w1.y, fmaf(s0.z, w2.y, fmaf(s0.w, w3.y, a0.y))));
      a0.z = fmaf(s0.x, w0.z, fmaf(s0.y, w1.z, fmaf(s0.z, w2.z, fmaf(s0.w, w3.z, a0.z))));
      a0.w = fmaf(s0.x, w0.w, fmaf(s0.y, w1.w, fmaf(s0.z, w2.w, fmaf(s0.w, w3.w, a0.w))));
      a1.x = fmaf(s1.x, w0.x, fmaf(s1.y, w1.x, fmaf(s1.z, w2.x, fmaf(s1.w, w3.x, a1.x))));
      a1.y = fmaf(s1.x, w0.y, fmaf(s1.y, w1.y, fmaf(s1.z, w2.y, fmaf(s1.w, w3.y, a1.y))));
      a1.z = fmaf(s1.x, w0.z, fmaf(s1.y, w1.z, fmaf(s1.z, w2.z, fmaf(s1.w, w3.z, a1.z))));
      a1.w = fmaf(s1.x, w0.w, fmaf(s1.y, w1.w, fmaf(s1.z, w2.w, fmaf(s1.w, w3.w, a1.w))));
    }
    float* h0 = &hid[ty * 260 + 4 * tx];
    float* h1 = &hid[(ty + 4) * 260 + 4 * tx];
    h0[0] = gelu_f(a0.x); h0[1] = gelu_f(a0.y); h0[2] = gelu_f(a0.z); h0[3] = gelu_f(a0.w);
    h1[0] = gelu_f(a1.x); h1[1] = gelu_f(a1.y); h1[2] = gelu_f(a1.z); h1[3] = gelu_f(a1.w);
  }
  __syncthreads();
  {  // GEMM2: [8,256] @ Wc2[256,64]; thread = 1 row x 2 cols
    int tx = tid & 31, ty = tid >> 5;
    float o0 = bc2[2 * tx], o1 = bc2[2 * tx + 1];
    const float4* h4 = (const float4*)&hid[ty * 260];
    const float* Wp = Wc2 + 2 * tx;
#pragma unroll 2
    for (int k4 = 0; k4 < 64; ++k4) {
      float2 w0 = *(const float2*)(Wp + (size_t)(4 * k4 + 0) * 64);
      float2 w1 = *(const float2*)(Wp + (size_t)(4 * k4 + 1) * 64);
      float2 w2 = *(const float2*)(Wp + (size_t)(4 * k4 + 2) * 64);
      float2 w3 = *(const float2*)(Wp + (size_t)(4 * k4 + 3) * 64);
      float4 t = h4[k4];
      o0 = fmaf(t.x, w0.x, fmaf(t.y, w1.x, fmaf(t.z, w2.x, fmaf(t.w, w3.x, o0))));
      o1 = fmaf(t.x, w0.y, fmaf(t.y, w1.y, fmaf(t.z, w2.y, fmaf(t.w, w3.y, o1))));
    }
    size_t oi = (r0 + ty) * 64 + 2 * tx;
    m[oi] = m[oi] + o0;
    m[oi + 1] = m[oi + 1] + o1;
  }
}

// K8: y = mean_n(x1+m); out = gelu(y@Wh1+bh1)@Wh2 + bh2. 4 waves per batch row.
__global__ void __launch_bounds__(256) k8_head(
    const float* __restrict__ x1, const float* __restrict__ m,
    const float* __restrict__ Wh1, const float* __restrict__ bh1,
    const float* __restrict__ Wh2, const float* __restrict__ bh2,
    float* __restrict__ out) {
  __shared__ float ysp[4 * 64];
  __shared__ float ys[64];
  int b = blockIdx.x, tid = threadIdx.x;
  int qtr = tid >> 6, lane = tid & 63;
  float acc = 0.f;
  for (int nn = qtr * 32; nn < qtr * 32 + 32; ++nn) {
    size_t oi = ((size_t)b * 128 + nn) * 64 + lane;
    acc += x1[oi] + m[oi];
  }
  ysp[qtr * 64 + lane] = acc;
  __syncthreads();
  if (tid < 64) ys[tid] = (ysp[tid] + ysp[64 + tid] + ysp[128 + tid] + ysp[192 + tid]) * (1.f / 128.f);
  __syncthreads();
  if (tid < 64) {
    float partial = 0.f;
    if (tid < 32) {
      float a = bh1[tid];
      for (int dd = 0; dd < 64; ++dd) a = fmaf(ys[dd], Wh1[dd * 32 + tid], a);
      partial = gelu_f(a) * Wh2[tid];
    }
    partial = wred(partial);
    if (tid == 0) out[b] = partial + bh2[0];
  }
}

extern "C" void kernel_launch(void* const* d_in, const int* in_sizes, int n_in,
                              void* d_out, int out_size, void* d_ws, size_t ws_size,
                              hipStream_t stream) {
  const float* x     = (const float*)d_in[0];
  const float* Wemb  = (const float*)d_in[1];
  const float* bemb  = (const float*)d_in[2];
  const float* rmsg  = (const float*)d_in[3];
  const float* Wq    = (const float*)d_in[4];
  const float* Wk    = (const float*)d_in[5];
  const float* Wv    = (const float*)d_in[6];
  const float* kpos  = (const float*)d_in[7];
  const float* vpos  = (const float*)d_in[8];
  const float* Wck   = (const float*)d_in[9];
  const float* bck   = (const float*)d_in[10];
  const float* Wcv   = (const float*)d_in[11];
  const float* bcv   = (const float*)d_in[12];
  const float* mck   = (const float*)d_in[13];
  const float* mcv   = (const float*)d_in[14];
  const float* Wg    = (const float*)d_in[15];
  const float* bg    = (const float*)d_in[16];
  const float* Wo    = (const float*)d_in[17];
  const float* ln1g  = (const float*)d_in[18];
  const float* ln1b  = (const float*)d_in[19];
  const float* Wt1   = (const float*)d_in[20];
  const float* bt1   = (const float*)d_in[21];
  const float* Wt2   = (const float*)d_in[22];
  const float* bt2   = (const float*)d_in[23];
  const float* ln2g  = (const float*)d_in[24];
  const float* ln2b  = (const float*)d_in[25];
  const float* Wc1   = (const float*)d_in[26];
  const float* bc1   = (const float*)d_in[27];
  const float* Wc2   = (const float*)d_in[28];
  const float* bc2   = (const float*)d_in[29];
  const float* Wh1   = (const float*)d_in[30];
  const float* bh1   = (const float*)d_in[31];
  const float* Wh2   = (const float*)d_in[32];
  const float* bh2   = (const float*)d_in[33];

  float* ws = (float*)d_ws;
  const size_t SZ_ROWD = (size_t)B_ * N_ * D_;        // 1,048,576
  const size_t SZ_BHND = (size_t)B_ * H_ * N_ * DH_;  // 8,388,608
  float* e    = ws;                    // SZ_ROWD
  float* lne  = e + SZ_ROWD;           // SZ_ROWD
  float* q    = lne + SZ_ROWD;         // SZ_BHND
  float* k    = q + SZ_BHND;           // SZ_BHND (x1 aliases after K4)
  float* v    = k + SZ_BHND;           // SZ_BHND (m aliases after K4)
  float* g    = v + SZ_BHND;           // B*N*24
  float* ckm  = g + (size_t)B_ * N_ * 24;         // B*H*33*64
  float* cvm  = ckm + (size_t)B_ * H_ * 33 * 64;  // B*H*33*64
  float* attn = cvm + (size_t)B_ * H_ * 33 * 64;  // B*N*512
  float* x1   = k;   // k dead after K4
  float* m    = v;   // v dead after K4

  k2_embed_proj<<<dim3(B_ * N_ / 32, 3), dim3(256), 0, stream>>>(
      x, Wemb, bemb, rmsg, ln1g, ln1b, Wq, Wk, Wv, Wg, bg, e, lne, q, k, v, g);
  k3_compress<<<dim3(B_ * H_), dim3(256), 0, stream>>>(k, v, kpos, vpos, Wck, bck, Wcv, bcv, mck, mcv, ckm, cvm);
  k4_attn<<<dim3(B_ * H_), dim3(128), 0, stream>>>(q, k, v, ckm, cvm, g, attn);
  k5_wo<<<dim3(B_ * N_ / 16), dim3(256), 0, stream>>>(attn, Wo, x1);
  k6_token<<<dim3(B_ * 16), dim3(256), 0, stream>>>(lne, e, Wt1, bt1, Wt2, bt2, m);
  k7_channel<<<dim3(B_ * N_ / 8), dim3(256), 0, stream>>>(m, ln2g, ln2b, Wc1, bc1, Wc2, bc2);
  k8_head<<<dim3(B_), dim3(256), 0, stream>>>(x1, m, Wh1, bh1, Wh2, bh2, (float*)d_out);
}

// Round 7
// 460.895 us; speedup vs baseline: 1.2342x; 1.2342x over previous
//
#include <hip/hip_runtime.h>
#include <math.h>

#define B_ 128
#define N_ 128
#define D_ 64
#define H_ 8
#define DH_ 64
#define NEGF (-1e30f)

__device__ __forceinline__ float wred(float v) {
#pragma unroll
  for (int off = 32; off > 0; off >>= 1) v += __shfl_xor(v, off, 64);
  return v;
}

__device__ __forceinline__ float gelu_f(float x) {
  return 0.5f * x * (1.f + erff(x * 0.70710678118654752440f));
}

// K2: fused embed + RMS + LN1 + projections. grid (512, 3): blockIdx.x = 32-row
// tile, blockIdx.y = chunk (Wq|Wk|Wv + 8 gate cols). Register tile: each thread
// 16 rows x 4 cols; LDS hs reads are full-wave broadcasts (1 b128 -> 16 FMA).
__global__ void __launch_bounds__(256) k2_embed_proj(
    const float* __restrict__ x, const float* __restrict__ Wemb,
    const float* __restrict__ bemb, const float* __restrict__ rmsg,
    const float* __restrict__ ln1g, const float* __restrict__ ln1b,
    const float* __restrict__ Wq, const float* __restrict__ Wk,
    const float* __restrict__ Wv, const float* __restrict__ Wg,
    const float* __restrict__ bg, float* __restrict__ e,
    float* __restrict__ lne, float* __restrict__ q,
    float* __restrict__ k, float* __restrict__ v, float* __restrict__ g) {
  __shared__ __align__(16) float hs[32 * 68];  // row stride 68: rows spread banks
  int tid = threadIdx.x;
  int r0 = blockIdx.x * 32;
  int chunk = blockIdx.y;
  int wave = tid >> 6, lane = tid & 63;
  // ---- embed + RMS + LN1 (8 rows per wave; chunk 0 writes e/lne) ----
  for (int rr = 0; rr < 8; ++rr) {
    int r = wave * 8 + rr;
    int row = r0 + r;
    float xv = x[row];
    float ev = fmaf(xv, Wemb[lane], bemb[lane]);
    float ss = wred(ev * ev) * (1.f / 64.f);
    float hv = ev * rsqrtf(ss + 1e-6f) * rmsg[lane];
    float mu = wred(ev) * (1.f / 64.f);
    float dv = ev - mu;
    float var = wred(dv * dv) * (1.f / 64.f);
    if (chunk == 0) {
      float lv = dv * rsqrtf(var + 1e-5f) * ln1g[lane] + ln1b[lane];
      size_t o = (size_t)row * 64 + lane;
      e[o] = ev; lne[o] = lv;
    }
    hs[r * 68 + lane] = hv;
  }
  __syncthreads();
  const float* W = (chunk == 0) ? Wq : ((chunk == 1) ? Wk : Wv);
  float* dst = (chunk == 0) ? q : ((chunk == 1) ? k : v);
  // ---- main GEMM: 32 rows x 512 cols; thread = 16 rows x 4 cols ----
  {
    int tx = tid & 127, ty = tid >> 7;  // cols 4*tx, rows ty*16..ty*16+15
    float4 acc[16];
#pragma unroll
    for (int r = 0; r < 16; ++r) acc[r] = make_float4(0.f, 0.f, 0.f, 0.f);
    const float* Wp = W + 4 * tx;
#pragma unroll 2
    for (int k4 = 0; k4 < 16; ++k4) {
      float4 w0 = *(const float4*)(Wp + (size_t)(4 * k4 + 0) * 512);
      float4 w1 = *(const float4*)(Wp + (size_t)(4 * k4 + 1) * 512);
      float4 w2 = *(const float4*)(Wp + (size_t)(4 * k4 + 2) * 512);
      float4 w3 = *(const float4*)(Wp + (size_t)(4 * k4 + 3) * 512);
#pragma unroll
      for (int r = 0; r < 16; ++r) {
        float4 hv = *(const float4*)&hs[(ty * 16 + r) * 68 + 4 * k4];
        acc[r].x = fmaf(hv.x, w0.x, fmaf(hv.y, w1.x, fmaf(hv.z, w2.x, fmaf(hv.w, w3.x, acc[r].x))));
        acc[r].y = fmaf(hv.x, w0.y, fmaf(hv.y, w1.y, fmaf(hv.z, w2.y, fmaf(hv.w, w3.y, acc[r].y))));
        acc[r].z = fmaf(hv.x, w0.z, fmaf(hv.y, w1.z, fmaf(hv.z, w2.z, fmaf(hv.w, w3.z, acc[r].z))));
        acc[r].w = fmaf(hv.x, w0.w, fmaf(hv.y, w1.w, fmaf(hv.z, w2.w, fmaf(hv.w, w3.w, acc[r].w))));
      }
    }
    int hh = (4 * tx) >> 6, d4 = (4 * tx) & 63;
    int bb = r0 >> 7;
    float* dbase = dst + ((size_t)(bb * 8 + hh) * 128) * 64 + d4;
#pragma unroll
    for (int r = 0; r < 16; ++r) {
      int nn = (r0 & 127) + ty * 16 + r;
      *(float4*)(dbase + (size_t)nn * 64) = acc[r];
    }
  }
  // ---- gate: 8 cols (chunk*8 .. +8) x 32 rows; thread = 1 output ----
  {
    int r = tid >> 3, gl = tid & 7;
    int gc = chunk * 8 + gl;
    float a = bg[gc];
#pragma unroll 4
    for (int k4 = 0; k4 < 16; ++k4) {
      float4 hv = *(const float4*)&hs[r * 68 + 4 * k4];
      a = fmaf(hv.x, Wg[(4 * k4 + 0) * 24 + gc],
          fmaf(hv.y, Wg[(4 * k4 + 1) * 24 + gc],
          fmaf(hv.z, Wg[(4 * k4 + 2) * 24 + gc],
          fmaf(hv.w, Wg[(4 * k4 + 3) * 24 + gc], a))));
    }
    g[(size_t)(r0 + r) * 24 + gc] = 1.f / (1.f + __expf(-a));
  }
}

// K3: per (b,h): ck = (k+kpos)@Wck+bck ; cv = (v+vpos)@Wcv+bcv; mem slot 0.
// Thread = 2 rows x 4 cols. LDS block-row stride 260 floats (256 + 4 pad).
__global__ void __launch_bounds__(256) k3_compress(
    const float* __restrict__ k, const float* __restrict__ v,
    const float* __restrict__ kpos, const float* __restrict__ vpos,
    const float* __restrict__ Wck, const float* __restrict__ bck,
    const float* __restrict__ Wcv, const float* __restrict__ bcv,
    const float* __restrict__ mck, const float* __restrict__ mcv,
    float* __restrict__ ckm, float* __restrict__ cvm) {
  __shared__ __align__(16) float sb[32 * 260];
  int bh = blockIdx.x; int hh = bh & 7;
  int tid = threadIdx.x;
  int tx = tid & 15, ty = tid >> 4;  // cols 4*tx; rows {ty, ty+16}
  const float4* sb4 = (const float4*)sb;  // block-row stride 65 float4
  for (int pass = 0; pass < 2; ++pass) {
    const float* src = pass ? v : k;
    const float* pos = pass ? vpos : kpos;
    const float* Wc = pass ? Wcv : Wck;
    const float* bc = pass ? bcv : bck;
    const float* mc = pass ? mcv : mck;
    float* out = pass ? cvm : ckm;
    if (pass) __syncthreads();
    for (int idx = tid; idx < 8192; idx += 256) {
      int tok = idx >> 6, dd = idx & 63;
      // block-row = tok>>2, within-row offset = (tok&3)*64 + dd  (stride 260)
      sb[(tok >> 2) * 260 + (tok & 3) * 64 + dd] =
          src[(size_t)bh * 8192 + idx] + pos[(hh * 4 + (tok & 3)) * 64 + dd];
    }
    __syncthreads();
    float4 b4 = *(const float4*)(bc + 4 * tx);
    float4 a0 = b4, a1 = b4;
    const float* Wp = Wc + 4 * tx;
#pragma unroll 2
    for (int k4 = 0; k4 < 64; ++k4) {
      float4 w0 = *(const float4*)(Wp + (size_t)(4 * k4 + 0) * 64);
      float4 w1 = *(const float4*)(Wp + (size_t)(4 * k4 + 1) * 64);
      float4 w2 = *(const float4*)(Wp + (size_t)(4 * k4 + 2) * 64);
      float4 w3 = *(const float4*)(Wp + (size_t)(4 * k4 + 3) * 64);
      float4 s0 = sb4[ty * 65 + k4];
      float4 s1 = sb4[(ty + 16) * 65 + k4];
      a0.x = fmaf(s0.x, w0.x, fmaf(s0.y, w1.x, fmaf(s0.z, w2.x, fmaf(s0.w, w3.x, a0.x))));
      a0.y = fmaf(s0.x, w0.y, fmaf(s0.y, w1.y, fmaf(s0.z, w2.y, fmaf(s0.w, w3.y, a0.y))));
      a0.z = fmaf(s0.x, w0.z, fmaf(s0.y, w1.z, fmaf(s0.z, w2.z, fmaf(s0.w, w3.z, a0.z))));
      a0.w = fmaf(s0.x, w0.w, fmaf(s0.y, w1.w, fmaf(s0.z, w2.w, fmaf(s0.w, w3.w, a0.w))));
      a1.x = fmaf(s1.x, w0.x, fmaf(s1.y, w1.x, fmaf(s1.z, w2.x, fmaf(s1.w, w3.x, a1.x))));
      a1.y = fmaf(s1.x, w0.y, fmaf(s1.y, w1.y, fmaf(s1.z, w2.y, fmaf(s1.w, w3.y, a1.y))));
      a1.z = fmaf(s1.x, w0.z, fmaf(s1.y, w1.z, fmaf(s1.z, w2.z, fmaf(s1.w, w3.z, a1.z))));
      a1.w = fmaf(s1.x, w0.w, fmaf(s1.y, w1.w, fmaf(s1.z, w2.w, fmaf(s1.w, w3.w, a1.w))));
    }
    *(float4*)(out + ((size_t)bh * 33 + ty + 1) * 64 + 4 * tx) = a0;
    *(float4*)(out + ((size_t)bh * 33 + ty + 17) * 64 + 4 * tx) = a1;
    if (tid < 16) *(float4*)(out + (size_t)bh * 2112 + 4 * tid) = *(const float4*)(mc + hh * 64 + 4 * tid);
  }
}

// K4: per (b,h): compressed + selected + window attention, gated combine.
// 1 thread = 1 query; scores in registers; PV in two d-halves (VGPR relief).
#define KLD 68
__global__ void __launch_bounds__(128, 2) k4_attn(
    const float* __restrict__ q, const float* __restrict__ k, const float* __restrict__ v,
    const float* __restrict__ ckm, const float* __restrict__ cvm, const float* __restrict__ g,
    float* __restrict__ attn) {
  __shared__ __align__(16) float ks[128 * KLD];  // K rows, later reloaded with V
  int bh = blockIdx.x; int b = bh >> 3, hh = bh & 7;
  int tid = threadIdx.x;
  for (int idx = tid; idx < 8192; idx += 128)
    ks[(idx >> 6) * KLD + (idx & 63)] = k[(size_t)bh * 8192 + idx];
  __syncthreads();
  const int n = tid;
  float4 qr[16];
  {
    const float4* q4 = (const float4*)(q + (size_t)bh * 8192 + (size_t)n * 64);
#pragma unroll
    for (int i = 0; i < 16; ++i) {
      float4 t = q4[i];
      t.x *= 0.125f; t.y *= 0.125f; t.z *= 0.125f; t.w *= 0.125f;
      qr[i] = t;
    }
  }
  auto dot = [&](const float4* __restrict__ rp) {
    float s0 = 0.f, s1 = 0.f;
#pragma unroll
    for (int i = 0; i < 16; i += 2) {
      float4 c0 = rp[i], c1 = rp[i + 1];
      s0 = fmaf(qr[i].x, c0.x, s0); s0 = fmaf(qr[i].y, c0.y, s0);
      s0 = fmaf(qr[i].z, c0.z, s0); s0 = fmaf(qr[i].w, c0.w, s0);
      s1 = fmaf(qr[i + 1].x, c1.x, s1); s1 = fmaf(qr[i + 1].y, c1.y, s1);
      s1 = fmaf(qr[i + 1].z, c1.z, s1); s1 = fmaf(qr[i + 1].w, c1.w, s1);
    }
    return s0 + s1;
  };
  const float* ck0 = ckm + (size_t)bh * 2112;
  const int jmax = (n + 1) >> 2;
  float scc[33];
#pragma unroll
  for (int j = 0; j < 33; ++j) {
    float s = dot((const float4*)(ck0 + j * 64));
    scc[j] = (j == 0 || j <= jmax) ? s : NEGF;
  }
  // exact top-2 (strict >, first index wins = lax.top_k ties)
  int i1 = 0; float b1 = scc[1];
#pragma unroll
  for (int j = 2; j < 33; ++j) {
    if (scc[j] > b1) { b1 = scc[j]; i1 = j - 1; }
  }
  int i2 = 0; float b2 = -3.0e38f;
#pragma unroll
  for (int j = 1; j < 33; ++j) {
    if ((j - 1 != i1) && (scc[j] > b2)) { b2 = scc[j]; i2 = j - 1; }
  }
  const int qb = n >> 2;
  const bool ok1 = (b1 > -5e29f) && (i1 != qb);
  const bool ok2 = (b2 > -5e29f) && (i2 != qb);
  const int row1 = i1 * 4, row2 = i2 * 4, rowd = qb * 4;
  float sf[12];
#pragma unroll
  for (int s2 = 0; s2 < 4; ++s2) {
    int t1 = row1 + s2;
    sf[s2] = (ok1 && t1 <= n) ? dot((const float4*)(ks + t1 * KLD)) : NEGF;
    int t2 = row2 + s2;
    sf[4 + s2] = (ok2 && t2 <= n) ? dot((const float4*)(ks + t2 * KLD)) : NEGF;
    int t3 = rowd + s2;
    sf[8 + s2] = (t3 <= n) ? dot((const float4*)(ks + t3 * KLD)) : NEGF;
  }
  float sw0 = (n >= 1) ? dot((const float4*)(ks + (n - 1) * KLD)) : NEGF;
  float sw1 = dot((const float4*)(ks + n * KLD));
  __syncthreads();
  for (int idx = tid; idx < 8192; idx += 128)  // reload LDS with V
    ks[(idx >> 6) * KLD + (idx & 63)] = v[(size_t)bh * 8192 + idx];
  __syncthreads();
  // softmaxes
  float mxc = scc[0];
#pragma unroll
  for (int j = 1; j < 33; ++j) mxc = fmaxf(mxc, scc[j]);
  float denc = 0.f;
#pragma unroll
  for (int j = 0; j < 33; ++j) { float p = __expf(scc[j] - mxc); scc[j] = p; denc += p; }
  float mxf = sf[0];
#pragma unroll
  for (int i = 1; i < 12; ++i) mxf = fmaxf(mxf, sf[i]);
  float denf = 0.f;
#pragma unroll
  for (int i = 0; i < 12; ++i) { float p = __expf(sf[i] - mxf); sf[i] = p; denf += p; }
  float mxw = fmaxf(sw0, sw1);
  float pw0 = __expf(sw0 - mxw), pw1 = __expf(sw1 - mxw);
  const float* gr = g + (size_t)(b * 128 + n) * 24;
  float gc0 = gr[hh] / denc;
  float gf0 = gr[8 + hh] / denf;
  float gw0 = gr[16 + hh] / (pw0 + pw1);
  float pww0 = pw0 * gw0, pww1 = pw1 * gw0;
  int nm1 = (n >= 1) ? (n - 1) : 0;
  const float* cv0 = cvm + (size_t)bh * 2112;
  float4* arow = (float4*)(attn + ((size_t)(b * 128 + n)) * 512 + hh * 64);
  for (int h2 = 0; h2 < 2; ++h2) {  // PV in two d-halves (not unrolled)
    float4 oa[8];
#pragma unroll
    for (int i = 0; i < 8; ++i) oa[i] = make_float4(0.f, 0.f, 0.f, 0.f);
#pragma unroll
    for (int j = 0; j < 33; ++j) {
      float p = scc[j] * gc0;
      const float4* cr = (const float4*)(cv0 + j * 64) + h2 * 8;
#pragma unroll
      for (int i = 0; i < 8; ++i) {
        float4 c = cr[i];
        oa[i].x = fmaf(p, c.x, oa[i].x); oa[i].y = fmaf(p, c.y, oa[i].y);
        oa[i].z = fmaf(p, c.z, oa[i].z); oa[i].w = fmaf(p, c.w, oa[i].w);
      }
    }
#pragma unroll
    for (int si = 0; si < 12; ++si) {
      int tok = ((si < 4) ? row1 : (si < 8) ? row2 : rowd) + (si & 3);
      float p = sf[si] * gf0;
      const float4* vr = (const float4*)(ks + tok * KLD) + h2 * 8;
#pragma unroll
      for (int i = 0; i < 8; ++i) {
        float4 c = vr[i];
        oa[i].x = fmaf(p, c.x, oa[i].x); oa[i].y = fmaf(p, c.y, oa[i].y);
        oa[i].z = fmaf(p, c.z, oa[i].z); oa[i].w = fmaf(p, c.w, oa[i].w);
      }
    }
    {
      const float4* v0 = (const float4*)(ks + nm1 * KLD) + h2 * 8;
      const float4* v1 = (const float4*)(ks + n * KLD) + h2 * 8;
#pragma unroll
      for (int i = 0; i < 8; ++i) {
        float4 c0 = v0[i], c1 = v1[i];
        oa[i].x = fmaf(pww0, c0.x, fmaf(pww1, c1.x, oa[i].x));
        oa[i].y = fmaf(pww0, c0.y, fmaf(pww1, c1.y, oa[i].y));
        oa[i].z = fmaf(pww0, c0.z, fmaf(pww1, c1.z, oa[i].z));
        oa[i].w = fmaf(pww0, c0.w, fmaf(pww1, c1.w, oa[i].w));
      }
    }
#pragma unroll
    for (int i = 0; i < 8; ++i) arow[h2 * 8 + i] = oa[i];
  }
}

// K5: x1 = attn @ Wo. 16 rows/block; thread = 1 row x 4 cols.
__global__ void __launch_bounds__(256) k5_wo(const float* __restrict__ attn,
                                             const float* __restrict__ Wo,
                                             float* __restrict__ x1) {
  __shared__ __align__(16) float as[16 * 516];
  int tid = threadIdx.x;
  size_t base = (size_t)blockIdx.x * 8192;
  for (int idx = tid; idx < 8192; idx += 256)
    as[(idx >> 9) * 516 + (idx & 511)] = attn[base + idx];
  __syncthreads();
  int tx = tid & 15, ty = tid >> 4;  // cols 4*tx, row ty
  const float4* as4 = (const float4*)as;  // row stride 129 float4
  float4 acc = make_float4(0.f, 0.f, 0.f, 0.f);
  const float* Wp = Wo + 4 * tx;
#pragma unroll 4
  for (int k4 = 0; k4 < 128; ++k4) {
    float4 w0 = *(const float4*)(Wp + (size_t)(4 * k4 + 0) * 64);
    float4 w1 = *(const float4*)(Wp + (size_t)(4 * k4 + 1) * 64);
    float4 w2 = *(const float4*)(Wp + (size_t)(4 * k4 + 2) * 64);
    float4 w3 = *(const float4*)(Wp + (size_t)(4 * k4 + 3) * 64);
    float4 a = as4[ty * 129 + k4];
    acc.x = fmaf(a.x, w0.x, fmaf(a.y, w1.x, fmaf(a.z, w2.x, fmaf(a.w, w3.x, acc.x))));
    acc.y = fmaf(a.x, w0.y, fmaf(a.y, w1.y, fmaf(a.z, w2.y, fmaf(a.w, w3.y, acc.y))));
    acc.z = fmaf(a.x, w0.z, fmaf(a.y, w1.z, fmaf(a.z, w2.z, fmaf(a.w, w3.z, acc.z))));
    acc.w = fmaf(a.x, w0.w, fmaf(a.y, w1.w, fmaf(a.z, w2.w, fmaf(a.w, w3.w, acc.w))));
  }
  *(float4*)(x1 + ((size_t)blockIdx.x * 16 + ty) * 64 + 4 * tx) = acc;
}

// K6: token mixer, L2-friendly: block = 32 (b,d)-rows of the flattened
// [B*D, N] problem (grid 256). trow/hid staged in LDS; all weight panels
// read once per wave (4x/block) instead of once per 4-d-column block.
__global__ void __launch_bounds__(256) k6_token(
    const float* __restrict__ lne, const float* __restrict__ e,
    const float* __restrict__ Wt1, const float* __restrict__ bt1,
    const float* __restrict__ Wt2, const float* __restrict__ bt2,
    float* __restrict__ m) {
  __shared__ __align__(16) float trow[32 * 132];  // t rows (later: GEMM2 out)
  __shared__ __align__(16) float hid[32 * 260];
  int b = blockIdx.x >> 1, d0 = (blockIdx.x & 1) * 32;
  int tid = threadIdx.x;
  // stage t = LN1(e)^T : trow[dl][nn]
  for (int idx = tid; idx < 4096; idx += 256) {
    int dl = idx & 31, nn = idx >> 5;
    trow[dl * 132 + nn] = lne[((size_t)b * 128 + nn) * 64 + d0 + dl];
  }
  __syncthreads();
  {  // GEMM1: [32,128] @ Wt1[128,256] -> gelu -> hid[32][256]; thread = 8r x 4c
    int tx = tid & 63, ty = tid >> 6;
    float4 bias = *(const float4*)(bt1 + 4 * tx);
    float4 acc[8];
#pragma unroll
    for (int r = 0; r < 8; ++r) acc[r] = bias;
    const float* Wp = Wt1 + 4 * tx;
#pragma unroll 2
    for (int k4 = 0; k4 < 32; ++k4) {
      float4 w0 = *(const float4*)(Wp + (size_t)(4 * k4 + 0) * 256);
      float4 w1 = *(const float4*)(Wp + (size_t)(4 * k4 + 1) * 256);
      float4 w2 = *(const float4*)(Wp + (size_t)(4 * k4 + 2) * 256);
      float4 w3 = *(const float4*)(Wp + (size_t)(4 * k4 + 3) * 256);
#pragma unroll
      for (int r = 0; r < 8; ++r) {
        float4 t = *(const float4*)&trow[(ty * 8 + r) * 132 + 4 * k4];
        acc[r].x = fmaf(t.x, w0.x, fmaf(t.y, w1.x, fmaf(t.z, w2.x, fmaf(t.w, w3.x, acc[r].x))));
        acc[r].y = fmaf(t.x, w0.y, fmaf(t.y, w1.y, fmaf(t.z, w2.y, fmaf(t.w, w3.y, acc[r].y))));
        acc[r].z = fmaf(t.x, w0.z, fmaf(t.y, w1.z, fmaf(t.z, w2.z, fmaf(t.w, w3.z, acc[r].z))));
        acc[r].w = fmaf(t.x, w0.w, fmaf(t.y, w1.w, fmaf(t.z, w2.w, fmaf(t.w, w3.w, acc[r].w))));
      }
    }
#pragma unroll
    for (int r = 0; r < 8; ++r) {
      float* hp = &hid[(ty * 8 + r) * 260 + 4 * tx];
      hp[0] = gelu_f(acc[r].x); hp[1] = gelu_f(acc[r].y);
      hp[2] = gelu_f(acc[r].z); hp[3] = gelu_f(acc[r].w);
    }
  }
  __syncthreads();
  {  // GEMM2: [32,256] @ Wt2[256,128] -> trow[32][128] (reuse); thread = 4r x 4c
    int tx = tid & 31, ty = tid >> 5;
    float4 bias = *(const float4*)(bt2 + 4 * tx);
    float4 acc[4];
#pragma unroll
    for (int r = 0; r < 4; ++r) acc[r] = bias;
    const float* Wp = Wt2 + 4 * tx;
#pragma unroll 2
    for (int k4 = 0; k4 < 64; ++k4) {
      float4 w0 = *(const float4*)(Wp + (size_t)(4 * k4 + 0) * 128);
      float4 w1 = *(const float4*)(Wp + (size_t)(4 * k4 + 1) * 128);
      float4 w2 = *(const float4*)(Wp + (size_t)(4 * k4 + 2) * 128);
      float4 w3 = *(const float4*)(Wp + (size_t)(4 * k4 + 3) * 128);
#pragma unroll
      for (int r = 0; r < 4; ++r) {
        float4 t = *(const float4*)&hid[(ty * 4 + r) * 260 + 4 * k4];
        acc[r].x = fmaf(t.x, w0.x, fmaf(t.y, w1.x, fmaf(t.z, w2.x, fmaf(t.w, w3.x, acc[r].x))));
        acc[r].y = fmaf(t.x, w0.y, fmaf(t.y, w1.y, fmaf(t.z, w2.y, fmaf(t.w, w3.y, acc[r].y))));
        acc[r].z = fmaf(t.x, w0.z, fmaf(t.y, w1.z, fmaf(t.z, w2.z, fmaf(t.w, w3.z, acc[r].z))));
        acc[r].w = fmaf(t.x, w0.w, fmaf(t.y, w1.w, fmaf(t.z, w2.w, fmaf(t.w, w3.w, acc[r].w))));
      }
    }
#pragma unroll
    for (int r = 0; r < 4; ++r)
      *(float4*)&trow[(ty * 4 + r) * 132 + 4 * tx] = acc[r];
  }
  __syncthreads();
  // write-back (transpose): m[b,nn,d] = e + trow[dl][nn]; coalesced over dl
  for (int idx = tid; idx < 4096; idx += 256) {
    int dl = idx & 31, nn = idx >> 5;
    size_t oi = ((size_t)b * 128 + nn) * 64 + d0 + dl;
    m[oi] = e[oi] + trow[dl * 132 + nn];
  }
}

// K7: channel MLP in-place, L2-friendly: 32 rows/block (grid 512).
__global__ void __launch_bounds__(256) k7_channel(
    float* __restrict__ m, const float* __restrict__ g2, const float* __restrict__ b2,
    const float* __restrict__ Wc1, const float* __restrict__ bc1,
    const float* __restrict__ Wc2, const float* __restrict__ bc2) {
  __shared__ __align__(16) float lnr[32 * 68];
  __shared__ __align__(16) float hid[32 * 260];
  int tid = threadIdx.x;
  int wv = tid >> 6, lane = tid & 63;
  size_t r0 = (size_t)blockIdx.x * 32;
  for (int rr = 0; rr < 8; ++rr) {
    int r = wv * 8 + rr;
    float mv = m[(r0 + r) * 64 + lane];
    float mu = wred(mv) * (1.f / 64.f);
    float dv = mv - mu;
    float var = wred(dv * dv) * (1.f / 64.f);
    lnr[r * 68 + lane] = dv * rsqrtf(var + 1e-5f) * g2[lane] + b2[lane];
  }
  __syncthreads();
  {  // GEMM1: [32,64] @ Wc1[64,256] -> gelu -> hid; thread = 8r x 4c
    int tx = tid & 63, ty = tid >> 6;
    float4 bias = *(const float4*)(bc1 + 4 * tx);
    float4 acc[8];
#pragma unroll
    for (int r = 0; r < 8; ++r) acc[r] = bias;
    const float* Wp = Wc1 + 4 * tx;
#pragma unroll 2
    for (int k4 = 0; k4 < 16; ++k4) {
      float4 w0 = *(const float4*)(Wp + (size_t)(4 * k4 + 0) * 256);
      float4 w1 = *(const float4*)(Wp + (size_t)(4 * k4 + 1) * 256);
      float4 w2 = *(const float4*)(Wp + (size_t)(4 * k4 + 2) * 256);
      float4 w3 = *(const float4*)(Wp + (size_t)(4 * k4 + 3) * 256);
#pragma unroll
      for (int r = 0; r < 8; ++r) {
        float4 t = *(const float4*)&lnr[(ty * 8 + r) * 68 + 4 * k4];
        acc[r].x = fmaf(t.x, w0.x, fmaf(t.y, w1.x, fmaf(t.z, w2.x, fmaf(t.w, w3.x, acc[r].x))));
        acc[r].y = fmaf(t.x, w0.y, fmaf(t.y, w1.y, fmaf(t.z, w2.y, fmaf(t.w, w3.y, acc[r].y))));
        acc[r].z = fmaf(t.x, w0.z, fmaf(t.y, w1.z, fmaf(t.z, w2.z, fmaf(t.w, w3.z, acc[r].z))));
        acc[r].w = fmaf(t.x, w0.w, fmaf(t.y, w1.w, fmaf(t.z, w2.w, fmaf(t.w, w3.w, acc[r].w))));
      }
    }
#pragma unroll
    for (int r = 0; r < 8; ++r) {
      float* hp = &hid[(ty * 8 + r) * 260 + 4 * tx];
      hp[0] = gelu_f(acc[r].x); hp[1] = gelu_f(acc[r].y);
      hp[2] = gelu_f(acc[r].z); hp[3] = gelu_f(acc[r].w);
    }
  }
  __syncthreads();
  {  // GEMM2: [32,256] @ Wc2[256,64] += m; thread = 2r x 4c
    int tx = tid & 15, ty = tid >> 4;
    float4 bias = *(const float4*)(bc2 + 4 * tx);
    float4 acc[2];
#pragma unroll
    for (int r = 0; r < 2; ++r) acc[r] = bias;
    const float* Wp = Wc2 + 4 * tx;
#pragma unroll 2
    for (int k4 = 0; k4 < 64; ++k4) {
      float4 w0 = *(const float4*)(Wp + (size_t)(4 * k4 + 0) * 64);
      float4 w1 = *(const float4*)(Wp + (size_t)(4 * k4 + 1) * 64);
      float4 w2 = *(const float4*)(Wp + (size_t)(4 * k4 + 2) * 64);
      float4 w3 = *(const float4*)(Wp + (size_t)(4 * k4 + 3) * 64);
#pragma unroll
      for (int r = 0; r < 2; ++r) {
        float4 t = *(const float4*)&hid[(ty * 2 + r) * 260 + 4 * k4];
        acc[r].x = fmaf(t.x, w0.x, fmaf(t.y, w1.x, fmaf(t.z, w2.x, fmaf(t.w, w3.x, acc[r].x))));
        acc[r].y = fmaf(t.x, w0.y, fmaf(t.y, w1.y, fmaf(t.z, w2.y, fmaf(t.w, w3.y, acc[r].y))));
        acc[r].z = fmaf(t.x, w0.z, fmaf(t.y, w1.z, fmaf(t.z, w2.z, fmaf(t.w, w3.z, acc[r].z))));
        acc[r].w = fmaf(t.x, w0.w, fmaf(t.y, w1.w, fmaf(t.z, w2.w, fmaf(t.w, w3.w, acc[r].w))));
      }
    }
#pragma unroll
    for (int r = 0; r < 2; ++r) {
      float4* mp = (float4*)(m + (r0 + ty * 2 + r) * 64 + 4 * tx);
      float4 old = *mp;
      old.x += acc[r].x; old.y += acc[r].y; old.z += acc[r].z; old.w += acc[r].w;
      *mp = old;
    }
  }
}

// K8: y = mean_n(x1+m); out = gelu(y@Wh1+bh1)@Wh2 + bh2. 4 waves per batch row.
__global__ void __launch_bounds__(256) k8_head(
    const float* __restrict__ x1, const float* __restrict__ m,
    const float* __restrict__ Wh1, const float* __restrict__ bh1,
    const float* __restrict__ Wh2, const float* __restrict__ bh2,
    float* __restrict__ out) {
  __shared__ float ysp[4 * 64];
  __shared__ float ys[64];
  int b = blockIdx.x, tid = threadIdx.x;
  int qtr = tid >> 6, lane = tid & 63;
  float acc = 0.f;
  for (int nn = qtr * 32; nn < qtr * 32 + 32; ++nn) {
    size_t oi = ((size_t)b * 128 + nn) * 64 + lane;
    acc += x1[oi] + m[oi];
  }
  ysp[qtr * 64 + lane] = acc;
  __syncthreads();
  if (tid < 64) ys[tid] = (ysp[tid] + ysp[64 + tid] + ysp[128 + tid] + ysp[192 + tid]) * (1.f / 128.f);
  __syncthreads();
  if (tid < 64) {
    float partial = 0.f;
    if (tid < 32) {
      float a = bh1[tid];
      for (int dd = 0; dd < 64; ++dd) a = fmaf(ys[dd], Wh1[dd * 32 + tid], a);
      partial = gelu_f(a) * Wh2[tid];
    }
    partial = wred(partial);
    if (tid == 0) out[b] = partial + bh2[0];
  }
}

extern "C" void kernel_launch(void* const* d_in, const int* in_sizes, int n_in,
                              void* d_out, int out_size, void* d_ws, size_t ws_size,
                              hipStream_t stream) {
  const float* x     = (const float*)d_in[0];
  const float* Wemb  = (const float*)d_in[1];
  const float* bemb  = (const float*)d_in[2];
  const float* rmsg  = (const float*)d_in[3];
  const float* Wq    = (const float*)d_in[4];
  const float* Wk    = (const float*)d_in[5];
  const float* Wv    = (const float*)d_in[6];
  const float* kpos  = (const float*)d_in[7];
  const float* vpos  = (const float*)d_in[8];
  const float* Wck   = (const float*)d_in[9];
  const float* bck   = (const float*)d_in[10];
  const float* Wcv   = (const float*)d_in[11];
  const float* bcv   = (const float*)d_in[12];
  const float* mck   = (const float*)d_in[13];
  const float* mcv   = (const float*)d_in[14];
  const float* Wg    = (const float*)d_in[15];
  const float* bg    = (const float*)d_in[16];
  const float* Wo    = (const float*)d_in[17];
  const float* ln1g  = (const float*)d_in[18];
  const float* ln1b  = (const float*)d_in[19];
  const float* Wt1   = (const float*)d_in[20];
  const float* bt1   = (const float*)d_in[21];
  const float* Wt2   = (const float*)d_in[22];
  const float* bt2   = (const float*)d_in[23];
  const float* ln2g  = (const float*)d_in[24];
  const float* ln2b  = (const float*)d_in[25];
  const float* Wc1   = (const float*)d_in[26];
  const float* bc1   = (const float*)d_in[27];
  const float* Wc2   = (const float*)d_in[28];
  const float* bc2   = (const float*)d_in[29];
  const float* Wh1   = (const float*)d_in[30];
  const float* bh1   = (const float*)d_in[31];
  const float* Wh2   = (const float*)d_in[32];
  const float* bh2   = (const float*)d_in[33];

  float* ws = (float*)d_ws;
  const size_t SZ_ROWD = (size_t)B_ * N_ * D_;        // 1,048,576
  const size_t SZ_BHND = (size_t)B_ * H_ * N_ * DH_;  // 8,388,608
  float* e    = ws;                    // SZ_ROWD
  float* lne  = e + SZ_ROWD;           // SZ_ROWD
  float* q    = lne + SZ_ROWD;         // SZ_BHND
  float* k    = q + SZ_BHND;           // SZ_BHND (x1 aliases after K4)
  float* v    = k + SZ_BHND;           // SZ_BHND (m aliases after K4)
  float* g    = v + SZ_BHND;           // B*N*24
  float* ckm  = g + (size_t)B_ * N_ * 24;         // B*H*33*64
  float* cvm  = ckm + (size_t)B_ * H_ * 33 * 64;  // B*H*33*64
  float* attn = cvm + (size_t)B_ * H_ * 33 * 64;  // B*N*512
  float* x1   = k;   // k dead after K4
  float* m    = v;   // v dead after K4

  k2_embed_proj<<<dim3(B_ * N_ / 32, 3), dim3(256), 0, stream>>>(
      x, Wemb, bemb, rmsg, ln1g, ln1b, Wq, Wk, Wv, Wg, bg, e, lne, q, k, v, g);
  k3_compress<<<dim3(B_ * H_), dim3(256), 0, stream>>>(k, v, kpos, vpos, Wck, bck, Wcv, bcv, mck, mcv, ckm, cvm);
  k4_attn<<<dim3(B_ * H_), dim3(128), 0, stream>>>(q, k, v, ckm, cvm, g, attn);
  k5_wo<<<dim3(B_ * N_ / 16), dim3(256), 0, stream>>>(attn, Wo, x1);
  k6_token<<<dim3(B_ * 2), dim3(256), 0, stream>>>(lne, e, Wt1, bt1, Wt2, bt2, m);
  k7_channel<<<dim3(B_ * N_ / 32), dim3(256), 0, stream>>>(m, ln2g, ln2b, Wc1, bc1, Wc2, bc2);
  k8_head<<<dim3(B_), dim3(256), 0, stream>>>(x1, m, Wh1, bh1, Wh2, bh2, (float*)d_out);
}